// Round 1
// baseline (6575.756 us; speedup 1.0000x reference)
//
#include <hip/hip_runtime.h>
#include <hip/hip_bf16.h>
#include <math.h>

#define Bdim 32
#define Ndim 512
#define Hdim 768
#define Rdim 5
#define Ldim 2
#define FFdim 1536
#define LN_EPS 1e-5f

#define BM 128
#define BN 128
#define BK 16

// ---------------------------------------------------------------------------
// Tiled fp32 GEMM with compile-time epilogue.
// EPI 0: C = (A@B) * rowscale[row]                     (agg: degree norm)
// EPI 1: C (+)= w[row>>9] * relu(A@B + bias[col])      (msg+gate merge)
// EPI 2: C = A@B + bias[col]                           (out proj / ffn2)
// EPI 3: C = relu(A@B + bias[col])                     (ffn1)
// ---------------------------------------------------------------------------
template <int EPI>
__global__ __launch_bounds__(256) void gemm_epi(
    const float* __restrict__ A, long sA, int lda,
    const float* __restrict__ Bm, long sB, int ldb,
    float* __restrict__ C, long sC, int ldc,
    int M, int Ncols, int K,
    const float* __restrict__ bias,
    const float* __restrict__ rs, long sRS,
    const float* __restrict__ wv, int wstride,
    int accumulate) {
  __shared__ float As[BK][BM + 4];
  __shared__ float Bs[BK][BN + 4];

  const int zb = blockIdx.z;
  const float* Ab = A + (long)zb * sA;
  const float* Bb = Bm + (long)zb * sB;
  float* Cb = C + (long)zb * sC;

  const int row0 = blockIdx.y * BM;
  const int col0 = blockIdx.x * BN;
  const int tid = threadIdx.x;

  const int a_r = tid >> 2;          // 0..63
  const int a_c4 = (tid & 3) * 4;    // 0,4,8,12
  const int b_r = tid >> 5;          // 0..7
  const int b_c4 = (tid & 31) * 4;   // 0..124
  const int tx = tid & 15;
  const int ty = tid >> 4;

  float acc[8][8];
#pragma unroll
  for (int i = 0; i < 8; i++)
#pragma unroll
    for (int j = 0; j < 8; j++) acc[i][j] = 0.f;

  for (int k0 = 0; k0 < K; k0 += BK) {
    // stage A tile (transposed into As[k][m]), rows a_r and a_r+64
#pragma unroll
    for (int i = 0; i < 2; i++) {
      const int r = row0 + a_r + i * 64;
      float4 v = *(const float4*)(Ab + (long)r * lda + k0 + a_c4);
      As[a_c4 + 0][a_r + i * 64] = v.x;
      As[a_c4 + 1][a_r + i * 64] = v.y;
      As[a_c4 + 2][a_r + i * 64] = v.z;
      As[a_c4 + 3][a_r + i * 64] = v.w;
    }
    // stage B tile (natural layout Bs[k][n])
#pragma unroll
    for (int i = 0; i < 2; i++) {
      const int r = k0 + b_r + i * 8;
      float4 v = *(const float4*)(Bb + (long)r * ldb + col0 + b_c4);
      *(float4*)&Bs[b_r + i * 8][b_c4] = v;
    }
    __syncthreads();

#pragma unroll
    for (int k = 0; k < BK; k++) {
      float4 a0 = *(const float4*)&As[k][ty * 8];
      float4 a1 = *(const float4*)&As[k][ty * 8 + 4];
      float4 b0 = *(const float4*)&Bs[k][tx * 8];
      float4 b1 = *(const float4*)&Bs[k][tx * 8 + 4];
      float av[8] = {a0.x, a0.y, a0.z, a0.w, a1.x, a1.y, a1.z, a1.w};
      float bv[8] = {b0.x, b0.y, b0.z, b0.w, b1.x, b1.y, b1.z, b1.w};
#pragma unroll
      for (int i = 0; i < 8; i++)
#pragma unroll
        for (int j = 0; j < 8; j++) acc[i][j] += av[i] * bv[j];
    }
    __syncthreads();
  }

  // epilogue
  float bvals[8];
  if (EPI >= 1) {
#pragma unroll
    for (int j = 0; j < 8; j++) bvals[j] = bias[col0 + tx * 8 + j];
  }
  float wval = 0.f;
  if (EPI == 1) wval = wv[(row0 >> 9) * wstride];

#pragma unroll
  for (int i = 0; i < 8; i++) {
    const int r = row0 + ty * 8 + i;
    float* cp = Cb + (long)r * ldc + col0 + tx * 8;
    float rsv = 0.f;
    if (EPI == 0) rsv = rs[(long)zb * sRS + r];
    float o[8];
#pragma unroll
    for (int j = 0; j < 8; j++) {
      float v = acc[i][j];
      if (EPI == 0) v = v * rsv;
      if (EPI == 1) v = wval * fmaxf(v + bvals[j], 0.f);
      if (EPI == 2) v = v + bvals[j];
      if (EPI == 3) v = fmaxf(v + bvals[j], 0.f);
      o[j] = v;
    }
    if (EPI == 1 && accumulate) {
      float4 e0 = *(const float4*)(cp);
      float4 e1 = *(const float4*)(cp + 4);
      o[0] += e0.x; o[1] += e0.y; o[2] += e0.z; o[3] += e0.w;
      o[4] += e1.x; o[5] += e1.y; o[6] += e1.z; o[7] += e1.w;
    }
    float4 s0 = {o[0], o[1], o[2], o[3]};
    float4 s1 = {o[4], o[5], o[6], o[7]};
    *(float4*)(cp) = s0;
    *(float4*)(cp + 4) = s1;
  }
}

// ---------------------------------------------------------------------------
// inv_deg[b,r,n] = 1 / max(sum_m adj[b,r,n,m], 1)   — one wave per row
// ---------------------------------------------------------------------------
__global__ __launch_bounds__(256) void deg_kernel(const float* __restrict__ adj,
                                                  float* __restrict__ inv_deg,
                                                  int total_rows) {
  const int w = (blockIdx.x * 256 + threadIdx.x) >> 6;
  const int lane = threadIdx.x & 63;
  if (w >= total_rows) return;
  const float* row = adj + (long)w * Ndim;
  float s = 0.f;
#pragma unroll
  for (int j = 0; j < Ndim / 64; j++) s += row[lane + j * 64];
#pragma unroll
  for (int off = 32; off > 0; off >>= 1) s += __shfl_down(s, off, 64);
  if (lane == 0) inv_deg[w] = 1.0f / fmaxf(s, 1.0f);
}

// ---------------------------------------------------------------------------
// gate: pooled = mean_n x[b,n,:]; logits = pooled@gW + gb; w = softmax(logits)
// one block per batch, 768 threads
// ---------------------------------------------------------------------------
__global__ void gate_kernel(const float* __restrict__ x,
                            const float* __restrict__ gW,
                            const float* __restrict__ gb,
                            float* __restrict__ w_out) {
  __shared__ float pooled[Hdim];
  __shared__ float logits[Rdim];
  const int b = blockIdx.x;
  const int h = threadIdx.x;
  const float* xb = x + (long)b * Ndim * Hdim + h;
  float s = 0.f;
  for (int n = 0; n < Ndim; n++) s += xb[(long)n * Hdim];
  pooled[h] = s * (1.0f / Ndim);
  __syncthreads();
  if (h < Rdim) {
    float acc = gb[h];
    for (int k = 0; k < Hdim; k++) acc += pooled[k] * gW[k * Rdim + h];
    logits[h] = acc;
  }
  __syncthreads();
  if (h == 0) {
    float mx = -1e30f;
    for (int r = 0; r < Rdim; r++) mx = fmaxf(mx, logits[r]);
    float e[Rdim];
    float se = 0.f;
    for (int r = 0; r < Rdim; r++) { e[r] = expf(logits[r] - mx); se += e[r]; }
    for (int r = 0; r < Rdim; r++) w_out[b * Rdim + r] = e[r] / se;
  }
}

// ---------------------------------------------------------------------------
// out = LayerNorm(a + bsrc) * g + beta   — one block (256 thr) per row of 768
// ---------------------------------------------------------------------------
__global__ __launch_bounds__(256) void ln_add_kernel(
    const float* __restrict__ A, const float* __restrict__ Bv,
    const float* __restrict__ g, const float* __restrict__ bb,
    float* __restrict__ out) {
  __shared__ float red[8];
  const long base = (long)blockIdx.x * Hdim;
  const int t = threadIdx.x;
  float v0 = A[base + t] + Bv[base + t];
  float v1 = A[base + t + 256] + Bv[base + t + 256];
  float v2 = A[base + t + 512] + Bv[base + t + 512];
  float s = v0 + v1 + v2;
  float ss = v0 * v0 + v1 * v1 + v2 * v2;
#pragma unroll
  for (int off = 32; off > 0; off >>= 1) {
    s += __shfl_down(s, off, 64);
    ss += __shfl_down(ss, off, 64);
  }
  const int wid = t >> 6;
  if ((t & 63) == 0) { red[wid] = s; red[4 + wid] = ss; }
  __syncthreads();
  s = red[0] + red[1] + red[2] + red[3];
  ss = red[4] + red[5] + red[6] + red[7];
  const float mu = s * (1.0f / Hdim);
  const float var = ss * (1.0f / Hdim) - mu * mu;
  const float inv = rsqrtf(var + LN_EPS);
  out[base + t] = (v0 - mu) * inv * g[t] + bb[t];
  out[base + t + 256] = (v1 - mu) * inv * g[t + 256] + bb[t + 256];
  out[base + t + 512] = (v2 - mu) * inv * g[t + 512] + bb[t + 512];
}

// ---------------------------------------------------------------------------
// relation_weights_stat[r] = mean over (l, b) of w
// ---------------------------------------------------------------------------
__global__ void stat_kernel(const float* __restrict__ w_buf, float* __restrict__ out) {
  const int r = threadIdx.x;
  if (r < Rdim) {
    float s = 0.f;
    for (int l = 0; l < Ldim; l++)
      for (int b = 0; b < Bdim; b++) s += w_buf[l * Bdim * Rdim + b * Rdim + r];
    out[r] = s * (1.0f / (Ldim * Bdim));
  }
}

extern "C" void kernel_launch(void* const* d_in, const int* in_sizes, int n_in,
                              void* d_out, int out_size, void* d_ws, size_t ws_size,
                              hipStream_t stream) {
  const float* node = (const float*)d_in[0];   // [B,N,H]
  const float* adj  = (const float*)d_in[1];   // [B,R,N,N]
  const float* relW = (const float*)d_in[2];   // [L,R,H,H]
  const float* relb = (const float*)d_in[3];   // [L,R,H]
  const float* gateW = (const float*)d_in[4];  // [L,H,R]
  const float* gateb = (const float*)d_in[5];  // [L,R]
  const float* outW = (const float*)d_in[6];   // [L,H,H]
  const float* outb = (const float*)d_in[7];   // [L,H]
  const float* ln1g = (const float*)d_in[8];
  const float* ln1b = (const float*)d_in[9];
  const float* fW1 = (const float*)d_in[10];   // [L,H,FF]
  const float* fb1 = (const float*)d_in[11];   // [L,FF]
  const float* fW2 = (const float*)d_in[12];   // [L,FF,H]
  const float* fb2 = (const float*)d_in[13];   // [L,H]
  const float* ln2g = (const float*)d_in[14];
  const float* ln2b = (const float*)d_in[15];

  const long BNH = (long)Bdim * Ndim * Hdim;      // 12,582,912
  float* xout = (float*)d_out;                    // final x lives here
  float* stat = xout + BNH;

  float* ws = (float*)d_ws;
  float* agg    = ws;                 // [B*N, H]   (also reused as tmp)
  float* merged = ws + BNH;           // [B*N, H]   (also reused as tmp2)
  float* hidden = ws + 2 * BNH;       // [B*N, H]
  float* ffh    = ws + 3 * BNH;       // [B*N, FF]  (2*BNH floats)
  float* inv_deg = ws + 5 * BNH;      // [B*R*N]
  float* w_buf   = inv_deg + (long)Bdim * Rdim * Ndim;  // [L*B*R]
  float* tmp = agg;
  float* tmp2 = merged;

  // degrees (layer-independent)
  {
    const int rows = Bdim * Rdim * Ndim;
    deg_kernel<<<(rows * 64 + 255) / 256, 256, 0, stream>>>(adj, inv_deg, rows);
  }

  for (int l = 0; l < Ldim; l++) {
    const float* xin = (l == 0) ? node : xout;

    // softmax gate (depends only on x)
    gate_kernel<<<Bdim, Hdim, 0, stream>>>(
        xin, gateW + (long)l * Hdim * Rdim, gateb + (long)l * Rdim,
        w_buf + (long)l * Bdim * Rdim);

    for (int r = 0; r < Rdim; r++) {
      // agg_r[b,n,h] = inv_deg[b,r,n] * sum_m adj[b,r,n,m] x[b,m,h]
      gemm_epi<0><<<dim3(Hdim / BN, Ndim / BM, Bdim), 256, 0, stream>>>(
          adj + (long)r * Ndim * Ndim, (long)Rdim * Ndim * Ndim, Ndim,
          xin, (long)Ndim * Hdim, Hdim,
          agg, (long)Ndim * Hdim, Hdim,
          Ndim, Hdim, Ndim,
          nullptr, inv_deg + (long)r * Ndim, (long)Rdim * Ndim, nullptr, 0, 0);

      // merged (+)= w[b,r] * relu(agg_r @ rel_W[l,r] + rel_b[l,r])
      gemm_epi<1><<<dim3(Hdim / BN, (Bdim * Ndim) / BM, 1), 256, 0, stream>>>(
          agg, 0, Hdim,
          relW + ((long)l * Rdim + r) * Hdim * Hdim, 0, Hdim,
          merged, 0, Hdim,
          Bdim * Ndim, Hdim, Hdim,
          relb + ((long)l * Rdim + r) * Hdim, nullptr, 0,
          w_buf + (long)l * Bdim * Rdim + r, Rdim, (r > 0) ? 1 : 0);
    }

    // tmp = merged @ out_W + out_b
    gemm_epi<2><<<dim3(Hdim / BN, (Bdim * Ndim) / BM, 1), 256, 0, stream>>>(
        merged, 0, Hdim, outW + (long)l * Hdim * Hdim, 0, Hdim,
        tmp, 0, Hdim, Bdim * Ndim, Hdim, Hdim,
        outb + (long)l * Hdim, nullptr, 0, nullptr, 0, 0);

    // hidden = LN(xin + tmp)
    ln_add_kernel<<<Bdim * Ndim, 256, 0, stream>>>(
        xin, tmp, ln1g + (long)l * Hdim, ln1b + (long)l * Hdim, hidden);

    // ffh = relu(hidden @ W1 + b1)
    gemm_epi<3><<<dim3(FFdim / BN, (Bdim * Ndim) / BM, 1), 256, 0, stream>>>(
        hidden, 0, Hdim, fW1 + (long)l * Hdim * FFdim, 0, FFdim,
        ffh, 0, FFdim, Bdim * Ndim, FFdim, Hdim,
        fb1 + (long)l * FFdim, nullptr, 0, nullptr, 0, 0);

    // tmp2 = ffh @ W2 + b2
    gemm_epi<2><<<dim3(Hdim / BN, (Bdim * Ndim) / BM, 1), 256, 0, stream>>>(
        ffh, 0, FFdim, fW2 + (long)l * FFdim * Hdim, 0, Hdim,
        tmp2, 0, Hdim, Bdim * Ndim, Hdim, FFdim,
        fb2 + (long)l * Hdim, nullptr, 0, nullptr, 0, 0);

    // x = LN(hidden + tmp2)  -> xout (d_out)
    ln_add_kernel<<<Bdim * Ndim, 256, 0, stream>>>(
        hidden, tmp2, ln2g + (long)l * Hdim, ln2b + (long)l * Hdim, xout);
  }

  stat_kernel<<<1, 64, 0, stream>>>(w_buf, stat);
}

// Round 4
// 2015.467 us; speedup vs baseline: 3.2626x; 3.2626x over previous
//
#include <hip/hip_runtime.h>
#include <hip/hip_bf16.h>
#include <math.h>

#define Bdim 32
#define Ndim 512
#define Hdim 768
#define Rdim 5
#define Ldim 2
#define FFdim 1536
#define LN_EPS 1e-5f

typedef __attribute__((ext_vector_type(8))) __bf16 bf16x8;
typedef __attribute__((ext_vector_type(8))) unsigned short ushort8;
typedef __attribute__((ext_vector_type(4))) float f32x4;

__device__ __forceinline__ unsigned short f2bf(float f) {
  union { float f; unsigned int u; } x;
  x.f = f;
  unsigned int u = x.u;
  return (unsigned short)((u + 0x7FFFu + ((u >> 16) & 1u)) >> 16);  // RTNE
}

// ---------------------------------------------------------------------------
// MFMA bf16 GEMM: C[M,N] = A[M,K] @ B[K,N], B supplied TRANSPOSED bf16
// (Bt[n][k], k-contiguous). A is fp32 (converted during staging) or bf16.
// 128x128 tile, BK=32, 4 waves x (64x64 quadrant as 4x4 MFMA 16x16 tiles).
// EPI 0: C = (A@B) * rs[row]            (agg: degree norm)       -> bf16 out
// EPI 1: C (+)= wv * relu(A@B + bias)   (msg + gate merge)       -> fp32 RMW
// EPI 2: C = A@B + bias                 (out proj / ffn2)        -> fp32
// EPI 3: C = relu(A@B + bias)           (ffn1)                   -> bf16 out
// ---------------------------------------------------------------------------
template <int EPI, bool A_F32, bool OUT_BF16>
__global__ __launch_bounds__(256) void mfma_gemm(
    const void* __restrict__ Ap, long sA, int lda,
    const unsigned short* __restrict__ Bt, long sB, int ldb,
    void* __restrict__ Cp, long sC, int ldc,
    int K,
    const float* __restrict__ bias,
    const float* __restrict__ rs, long sRS,
    const float* __restrict__ wv,
    int accumulate) {
  __shared__ __align__(16) unsigned short As[128][40];
  __shared__ __align__(16) unsigned short Bs[128][40];

  const int zb = blockIdx.z;
  const int row0 = blockIdx.y * 128;
  const int col0 = blockIdx.x * 128;
  const int tid = threadIdx.x;
  const int wid = tid >> 6;
  const int lane = tid & 63;
  const int mq = (wid & 1) * 64;   // wave's row quadrant
  const int nq = (wid >> 1) * 64;  // wave's col quadrant
  const int lr = lane & 15;
  const int lk = (lane >> 4) * 8;

  // staging assignment: thread t covers tile-row sr, k-halves of 16
  const int sr = tid >> 1;
  const int sk = (tid & 1) * 16;

  const unsigned short* Btb = Bt + zb * sB;

  f32x4 acc[4][4];
#pragma unroll
  for (int i = 0; i < 4; i++)
#pragma unroll
    for (int j = 0; j < 4; j++) acc[i][j] = (f32x4){0.f, 0.f, 0.f, 0.f};

  for (int k0 = 0; k0 < K; k0 += 32) {
    // ---- stage A tile ----
    if (A_F32) {
      const float* ap = (const float*)Ap + zb * sA + (long)(row0 + sr) * lda + k0 + sk;
      float4 f0 = *(const float4*)(ap);
      float4 f1 = *(const float4*)(ap + 4);
      float4 f2 = *(const float4*)(ap + 8);
      float4 f3 = *(const float4*)(ap + 12);
      ushort8 h0 = {f2bf(f0.x), f2bf(f0.y), f2bf(f0.z), f2bf(f0.w),
                    f2bf(f1.x), f2bf(f1.y), f2bf(f1.z), f2bf(f1.w)};
      ushort8 h1 = {f2bf(f2.x), f2bf(f2.y), f2bf(f2.z), f2bf(f2.w),
                    f2bf(f3.x), f2bf(f3.y), f2bf(f3.z), f2bf(f3.w)};
      *(ushort8*)&As[sr][sk] = h0;
      *(ushort8*)&As[sr][sk + 8] = h1;
    } else {
      const unsigned short* ap =
          (const unsigned short*)Ap + zb * sA + (long)(row0 + sr) * lda + k0 + sk;
      ushort8 h0 = *(const ushort8*)(ap);
      ushort8 h1 = *(const ushort8*)(ap + 8);
      *(ushort8*)&As[sr][sk] = h0;
      *(ushort8*)&As[sr][sk + 8] = h1;
    }
    // ---- stage B tile (already transposed bf16) ----
    {
      const unsigned short* bp = Btb + (long)(col0 + sr) * ldb + k0 + sk;
      ushort8 h0 = *(const ushort8*)(bp);
      ushort8 h1 = *(const ushort8*)(bp + 8);
      *(ushort8*)&Bs[sr][sk] = h0;
      *(ushort8*)&Bs[sr][sk + 8] = h1;
    }
    __syncthreads();

    bf16x8 af[4], bfr[4];
#pragma unroll
    for (int i = 0; i < 4; i++) af[i] = *(const bf16x8*)&As[mq + i * 16 + lr][lk];
#pragma unroll
    for (int j = 0; j < 4; j++) bfr[j] = *(const bf16x8*)&Bs[nq + j * 16 + lr][lk];
#pragma unroll
    for (int i = 0; i < 4; i++)
#pragma unroll
      for (int j = 0; j < 4; j++)
        acc[i][j] = __builtin_amdgcn_mfma_f32_16x16x32_bf16(af[i], bfr[j], acc[i][j], 0, 0, 0);
    __syncthreads();
  }

  // ---- epilogue ----
  float bvals[4];
  if (EPI >= 1) {
#pragma unroll
    for (int j = 0; j < 4; j++) bvals[j] = bias[col0 + nq + j * 16 + lr];
  }
  float wval = 0.f;
  if (EPI == 1) wval = wv[(row0 >> 9) * Rdim];

  float* Cf = (float*)Cp;
  unsigned short* Ch = (unsigned short*)Cp;

#pragma unroll
  for (int i = 0; i < 4; i++) {
#pragma unroll
    for (int r = 0; r < 4; r++) {
      const int grow = row0 + mq + i * 16 + (lane >> 4) * 4 + r;
      float rsv = 0.f;
      if (EPI == 0) rsv = rs[zb * sRS + grow];
#pragma unroll
      for (int j = 0; j < 4; j++) {
        const int gcol = col0 + nq + j * 16 + lr;
        const long cidx = zb * sC + (long)grow * ldc + gcol;
        float v = acc[i][j][r];
        if (EPI == 0) v *= rsv;
        if (EPI == 1) {
          v = wval * fmaxf(v + bvals[j], 0.f);
          if (accumulate) v += Cf[cidx];
        }
        if (EPI == 2) v += bvals[j];
        if (EPI == 3) v = fmaxf(v + bvals[j], 0.f);
        if (OUT_BF16) Ch[cidx] = f2bf(v);
        else Cf[cidx] = v;
      }
    }
  }
}

// ---------------------------------------------------------------------------
// transpose + fp32->bf16 convert: in[z][R_][C_] f32 -> out[z][C_][R_] bf16
// ---------------------------------------------------------------------------
__global__ __launch_bounds__(256) void transpose_cvt(
    const float* __restrict__ in, unsigned short* __restrict__ out, int R_, int C_) {
  __shared__ float t[32][33];
  const int z = blockIdx.z;
  const float* ib = in + (long)z * R_ * C_;
  unsigned short* ob = out + (long)z * R_ * C_;
  const int r0 = blockIdx.y * 32, c0 = blockIdx.x * 32;
  const int tx = threadIdx.x & 31, ty = threadIdx.x >> 5;
#pragma unroll
  for (int i = 0; i < 4; i++)
    t[ty + i * 8][tx] = ib[(long)(r0 + ty + i * 8) * C_ + c0 + tx];
  __syncthreads();
#pragma unroll
  for (int i = 0; i < 4; i++)
    ob[(long)(c0 + ty + i * 8) * R_ + r0 + tx] = f2bf(t[tx][ty + i * 8]);
}

// ---------------------------------------------------------------------------
// inv_deg[b,r,n] = 1 / max(sum_m adj[b,r,n,m], 1)   — one wave per row
// ---------------------------------------------------------------------------
__global__ __launch_bounds__(256) void deg_kernel(const float* __restrict__ adj,
                                                  float* __restrict__ inv_deg,
                                                  int total_rows) {
  const int w = (blockIdx.x * 256 + threadIdx.x) >> 6;
  const int lane = threadIdx.x & 63;
  if (w >= total_rows) return;
  const float* row = adj + (long)w * Ndim;
  float s = 0.f;
#pragma unroll
  for (int j = 0; j < Ndim / 64; j++) s += row[lane + j * 64];
#pragma unroll
  for (int off = 32; off > 0; off >>= 1) s += __shfl_down(s, off, 64);
  if (lane == 0) inv_deg[w] = 1.0f / fmaxf(s, 1.0f);
}

// ---------------------------------------------------------------------------
// gate: pooled = mean_n x[b,n,:]; logits = pooled@gW + gb; w = softmax(logits)
// ---------------------------------------------------------------------------
__global__ void gate_kernel(const float* __restrict__ x,
                            const float* __restrict__ gW,
                            const float* __restrict__ gb,
                            float* __restrict__ w_out) {
  __shared__ float pooled[Hdim];
  __shared__ float logits[Rdim];
  const int b = blockIdx.x;
  const int h = threadIdx.x;
  const float* xb = x + (long)b * Ndim * Hdim + h;
  float s = 0.f;
  for (int n = 0; n < Ndim; n++) s += xb[(long)n * Hdim];
  pooled[h] = s * (1.0f / Ndim);
  __syncthreads();
  if (h < Rdim) {
    float acc = gb[h];
    for (int k = 0; k < Hdim; k++) acc += pooled[k] * gW[k * Rdim + h];
    logits[h] = acc;
  }
  __syncthreads();
  if (h == 0) {
    float mx = -1e30f;
    for (int r = 0; r < Rdim; r++) mx = fmaxf(mx, logits[r]);
    float e[Rdim];
    float se = 0.f;
    for (int r = 0; r < Rdim; r++) { e[r] = expf(logits[r] - mx); se += e[r]; }
    for (int r = 0; r < Rdim; r++) w_out[b * Rdim + r] = e[r] / se;
  }
}

// ---------------------------------------------------------------------------
// out = LayerNorm(a + bsrc) * g + beta   — one block (256 thr) per row of 768
// ---------------------------------------------------------------------------
__global__ __launch_bounds__(256) void ln_add_kernel(
    const float* __restrict__ A, const float* __restrict__ Bv,
    const float* __restrict__ g, const float* __restrict__ bb,
    float* __restrict__ out) {
  __shared__ float red[8];
  const long base = (long)blockIdx.x * Hdim;
  const int t = threadIdx.x;
  float v0 = A[base + t] + Bv[base + t];
  float v1 = A[base + t + 256] + Bv[base + t + 256];
  float v2 = A[base + t + 512] + Bv[base + t + 512];
  float s = v0 + v1 + v2;
  float ss = v0 * v0 + v1 * v1 + v2 * v2;
#pragma unroll
  for (int off = 32; off > 0; off >>= 1) {
    s += __shfl_down(s, off, 64);
    ss += __shfl_down(ss, off, 64);
  }
  const int wid = t >> 6;
  if ((t & 63) == 0) { red[wid] = s; red[4 + wid] = ss; }
  __syncthreads();
  s = red[0] + red[1] + red[2] + red[3];
  ss = red[4] + red[5] + red[6] + red[7];
  const float mu = s * (1.0f / Hdim);
  const float var = ss * (1.0f / Hdim) - mu * mu;
  const float inv = rsqrtf(var + LN_EPS);
  out[base + t] = (v0 - mu) * inv * g[t] + bb[t];
  out[base + t + 256] = (v1 - mu) * inv * g[t + 256] + bb[t + 256];
  out[base + t + 512] = (v2 - mu) * inv * g[t + 512] + bb[t + 512];
}

// ---------------------------------------------------------------------------
__global__ void stat_kernel(const float* __restrict__ w_buf, float* __restrict__ out) {
  const int r = threadIdx.x;
  if (r < Rdim) {
    float s = 0.f;
    for (int l = 0; l < Ldim; l++)
      for (int b = 0; b < Bdim; b++) s += w_buf[l * Bdim * Rdim + b * Rdim + r];
    out[r] = s * (1.0f / (Ldim * Bdim));
  }
}

extern "C" void kernel_launch(void* const* d_in, const int* in_sizes, int n_in,
                              void* d_out, int out_size, void* d_ws, size_t ws_size,
                              hipStream_t stream) {
  const float* node = (const float*)d_in[0];   // [B,N,H]
  const float* adj  = (const float*)d_in[1];   // [B,R,N,N]
  const float* relW = (const float*)d_in[2];   // [L,R,H,H]
  const float* relb = (const float*)d_in[3];   // [L,R,H]
  const float* gateW = (const float*)d_in[4];  // [L,H,R]
  const float* gateb = (const float*)d_in[5];  // [L,R]
  const float* outW = (const float*)d_in[6];   // [L,H,H]
  const float* outb = (const float*)d_in[7];   // [L,H]
  const float* ln1g = (const float*)d_in[8];
  const float* ln1b = (const float*)d_in[9];
  const float* fW1 = (const float*)d_in[10];   // [L,H,FF]
  const float* fb1 = (const float*)d_in[11];   // [L,FF]
  const float* fW2 = (const float*)d_in[12];   // [L,FF,H]
  const float* fb2 = (const float*)d_in[13];   // [L,H]
  const float* ln2g = (const float*)d_in[14];
  const float* ln2b = (const float*)d_in[15];

  const long BNH = (long)Bdim * Ndim * Hdim;   // 12,582,912
  float* xout = (float*)d_out;
  float* stat = xout + BNH;

  // ws layout (float units)
  float* ws = (float*)d_ws;
  float* merged = ws;                          // [B*N,H] f32 (accum); later tmp2
  float* hidden = ws + BNH;                    // [B*N,H] f32
  float* tmp    = ws + 2 * BNH;                // [B*N,H] f32; later aliased by ffh
  unsigned short* agg_bf = (unsigned short*)(ws + 3 * BNH);        // [B*N,H] bf16
  unsigned short* xT_bf  = (unsigned short*)(ws + 3 * BNH + BNH / 2); // [B,H,N] bf16
  unsigned short* relWT  = (unsigned short*)(ws + 4 * BNH);        // [L*R,H,H] bf16
  unsigned short* outWT  = relWT + (long)Ldim * Rdim * Hdim * Hdim;
  unsigned short* W1T    = outWT + (long)Ldim * Hdim * Hdim;
  unsigned short* W2T    = W1T + (long)Ldim * Hdim * FFdim;
  float* inv_deg = (float*)(W2T + (long)Ldim * FFdim * Hdim);
  float* w_buf = inv_deg + (long)Bdim * Rdim * Ndim;
  unsigned short* ffh_bf = (unsigned short*)tmp;  // [B*N,FF] bf16 (aliases tmp)
  float* tmp2 = merged;                           // aliases merged

  // ---- one-time prep ----
  {
    const int rows = Bdim * Rdim * Ndim;
    deg_kernel<<<(rows * 64 + 255) / 256, 256, 0, stream>>>(adj, inv_deg, rows);
  }
  transpose_cvt<<<dim3(Hdim / 32, Hdim / 32, Ldim * Rdim), 256, 0, stream>>>(relW, relWT, Hdim, Hdim);
  transpose_cvt<<<dim3(Hdim / 32, Hdim / 32, Ldim), 256, 0, stream>>>(outW, outWT, Hdim, Hdim);
  transpose_cvt<<<dim3(FFdim / 32, Hdim / 32, Ldim), 256, 0, stream>>>(fW1, W1T, Hdim, FFdim);
  transpose_cvt<<<dim3(Hdim / 32, FFdim / 32, Ldim), 256, 0, stream>>>(fW2, W2T, FFdim, Hdim);

  for (int l = 0; l < Ldim; l++) {
    const float* xin = (l == 0) ? node : xout;

    gate_kernel<<<Bdim, Hdim, 0, stream>>>(
        xin, gateW + (long)l * Hdim * Rdim, gateb + (long)l * Rdim,
        w_buf + (long)l * Bdim * Rdim);

    // xT_bf[b][h][n] = x[b][n][h]
    transpose_cvt<<<dim3(Hdim / 32, Ndim / 32, Bdim), 256, 0, stream>>>(xin, xT_bf, Ndim, Hdim);

    for (int r = 0; r < Rdim; r++) {
      // agg_bf[b,n,:] = inv_deg[b,r,n] * (adj[b,r] @ x[b])
      mfma_gemm<0, true, true><<<dim3(Hdim / 128, Ndim / 128, Bdim), 256, 0, stream>>>(
          adj + (long)r * Ndim * Ndim, (long)Rdim * Ndim * Ndim, Ndim,
          xT_bf, (long)Hdim * Ndim, Ndim,
          agg_bf, (long)Ndim * Hdim, Hdim,
          Ndim,
          nullptr, inv_deg + (long)r * Ndim, (long)Rdim * Ndim, nullptr, 0);

      // merged (+)= w[b,r] * relu(agg @ rel_W[l,r] + rel_b[l,r])
      mfma_gemm<1, false, false><<<dim3(Hdim / 128, (Bdim * Ndim) / 128, 1), 256, 0, stream>>>(
          agg_bf, 0, Hdim,
          relWT + ((long)l * Rdim + r) * Hdim * Hdim, 0, Hdim,
          merged, 0, Hdim,
          Hdim,
          relb + ((long)l * Rdim + r) * Hdim, nullptr, 0,
          w_buf + (long)l * Bdim * Rdim + r, (r > 0) ? 1 : 0);
    }

    // tmp = merged @ out_W + out_b
    mfma_gemm<2, true, false><<<dim3(Hdim / 128, (Bdim * Ndim) / 128, 1), 256, 0, stream>>>(
        merged, 0, Hdim,
        outWT + (long)l * Hdim * Hdim, 0, Hdim,
        tmp, 0, Hdim,
        Hdim,
        outb + (long)l * Hdim, nullptr, 0, nullptr, 0);

    // hidden = LN(xin + tmp)
    ln_add_kernel<<<Bdim * Ndim, 256, 0, stream>>>(
        xin, tmp, ln1g + (long)l * Hdim, ln1b + (long)l * Hdim, hidden);

    // ffh = relu(hidden @ W1 + b1)  -> bf16 (aliases tmp, which is now dead)
    mfma_gemm<3, true, true><<<dim3(FFdim / 128, (Bdim * Ndim) / 128, 1), 256, 0, stream>>>(
        hidden, 0, Hdim,
        W1T + (long)l * Hdim * FFdim, 0, Hdim,
        ffh_bf, 0, FFdim,
        Hdim,
        fb1 + (long)l * FFdim, nullptr, 0, nullptr, 0);

    // tmp2 = ffh @ W2 + b2   (aliases merged, dead after out-proj)
    mfma_gemm<2, false, false><<<dim3(Hdim / 128, (Bdim * Ndim) / 128, 1), 256, 0, stream>>>(
        ffh_bf, 0, FFdim,
        W2T + (long)l * FFdim * Hdim, 0, FFdim,
        tmp2, 0, Hdim,
        FFdim,
        fb2 + (long)l * Hdim, nullptr, 0, nullptr, 0);

    // x = LN(hidden + tmp2) -> xout
    ln_add_kernel<<<Bdim * Ndim, 256, 0, stream>>>(
        hidden, tmp2, ln2g + (long)l * Hdim, ln2b + (long)l * Hdim, xout);
  }

  stat_kernel<<<1, 64, 0, stream>>>(w_buf, stat);
}